// Round 9
// baseline (434.989 us; speedup 1.0000x reference)
//
#include <hip/hip_runtime.h>
#include <hip/hip_bf16.h>

typedef __bf16 bf16;
typedef __attribute__((ext_vector_type(8))) __bf16 bf16x8;
typedef __attribute__((ext_vector_type(4))) __bf16 bf16x4;
typedef __attribute__((ext_vector_type(4))) float f32x4;

// ---------------------------------------------------------------- constants
#define B_SZ 2
#define S_SZ 2048
#define D_SZ 2048
#define H_SZ 32
#define KV_SZ 8
#define HD_SZ 64
#define M_SZ (B_SZ * S_SZ)   // 4096
#define NQKV 3072            // 2048 Q + 512 K + 512 V packed weight rows

// async global->LDS, 16B per lane; LDS dest = wave-uniform base + lane*16
#define GLDS(g, s) __builtin_amdgcn_global_load_lds( \
    (const __attribute__((address_space(1))) void*)(g), \
    (__attribute__((address_space(3))) void*)(s), 16, 0, 0)

// lgkm-only barrier: do NOT drain vmcnt (in-flight global loads cross the
// barrier; their completion is waited where the data is consumed).
__device__ __forceinline__ void bar_lgkm() {
    asm volatile("s_waitcnt lgkmcnt(0)\n\ts_barrier" ::: "memory");
}

// ---------------------------------------------------------------- fused conversions
// single dispatch: x -> xb, [Wq;Wk;Wv] -> Wf, Wo -> wob (all bf16)
__global__ void cvt_all(const float* __restrict__ x, const float* __restrict__ Wq,
                        const float* __restrict__ Wk, const float* __restrict__ Wv,
                        const float* __restrict__ Wo,
                        bf16* __restrict__ xb, bf16* __restrict__ Wf, bf16* __restrict__ wob,
                        int nx, int n1, int n2) {
    int i = blockIdx.x * blockDim.x + threadIdx.x;
    const float* src; bf16* dst; int off;
    if (i < nx)                 { src = x;  dst = xb; off = i; }
    else {
        int j = i - nx;
        if (j < n1)             { src = Wq; dst = Wf; off = j; }
        else if (j < n1 + n2)   { src = Wk; dst = Wf + (size_t)4 * n1; off = j - n1; }
        else if (j < n1 + 2*n2) { src = Wv; dst = Wf + (size_t)4 * (n1 + n2); off = j - n1 - n2; }
        else if (j < 2*n1+2*n2) { src = Wo; dst = wob; off = j - n1 - 2 * n2; }
        else return;
    }
    float4 v = ((const float4*)src)[off];
    bf16x4 o;
    o.x = (bf16)v.x; o.y = (bf16)v.y; o.z = (bf16)v.z; o.w = (bf16)v.w;
    ((bf16x4*)dst)[off] = o;
}

// ---------------------------------------------------------------- GEMM core: 2-phase dbuf
// 256 threads / 4 waves; wave (wr,wc) owns the 64x64 quadrant; acc[4][4].
// T3-minimum pipeline: LDS double buffer (2 x 32KB); next tile's 8
// global_load_lds issued BEFORE computing the current tile, in flight across
// the trailing lgkm-only barrier; head waits vmcnt(8) (T4 counted-vmcnt).
// XOR chunk swizzle (chunk q of row r at q^(r&7)); staging lane l fetches
// global chunk (l&7)^(l>>3) so LDS writes are linear; b128 reads conflict-free.
#define GEMM_CORE5(A_, B_, Kdim)                                                 \
    const int tid  = threadIdx.x;                                                \
    const int wv   = tid >> 6;                                                   \
    const int lane = tid & 63;                                                   \
    const int c = lane & 15, quad = lane >> 4;                                   \
    const int wr = wv >> 1, wc = wv & 1;                                         \
    const int g8 = lane >> 3;                                                    \
    const int chs = ((lane & 7) ^ g8) * 8;                                       \
    const int rowBase = blockIdx.y * 128;                                        \
    const int colBase = blockIdx.x * 128;                                        \
    const bf16* Ag = A_ + (size_t)(rowBase + wv * 32 + g8) * Kdim + chs;         \
    const bf16* Bg = B_ + (size_t)(colBase + wv * 32 + g8) * Kdim + chs;         \
    f32x4 acc[4][4] = {};                                                        \
    _Pragma("unroll")                                                            \
    for (int j = 0; j < 4; j++) {       /* prologue: stage tile 0 -> buf 0 */    \
        GLDS(Ag + (size_t)(j * 8) * Kdim, Ls + (wv * 32 + j * 8) * 64);          \
        GLDS(Bg + (size_t)(j * 8) * Kdim, Ls + 8192 + (wv * 32 + j * 8) * 64);   \
    }                                                                            \
    for (int k0 = 0; k0 < Kdim; k0 += 64) {                                      \
        bf16* Asb = Ls + ((k0 >> 6) & 1) * 16384;                                \
        bf16* Bsb = Asb + 8192;                                                  \
        if (k0 + 64 < Kdim) {           /* issue next tile into other buf */     \
            bf16* Asn = Ls + ((((k0 >> 6) & 1) ^ 1) * 16384);                    \
            _Pragma("unroll")                                                    \
            for (int j = 0; j < 4; j++) {                                        \
                GLDS(Ag + (size_t)(j * 8) * Kdim + (k0 + 64),                    \
                     Asn + (wv * 32 + j * 8) * 64);                              \
                GLDS(Bg + (size_t)(j * 8) * Kdim + (k0 + 64),                    \
                     Asn + 8192 + (wv * 32 + j * 8) * 64);                       \
            }                                                                    \
            asm volatile("s_waitcnt vmcnt(8)" ::: "memory");                     \
        } else {                                                                 \
            asm volatile("s_waitcnt vmcnt(0)" ::: "memory");                     \
        }                                                                        \
        asm volatile("s_waitcnt lgkmcnt(0)\n\ts_barrier" ::: "memory");          \
        _Pragma("unroll")                                                        \
        for (int ks = 0; ks < 2; ks++) {                                         \
            bf16x8 af[4], bfr[4];                                                \
            _Pragma("unroll")                                                    \
            for (int mi = 0; mi < 4; mi++)                                       \
                af[mi] = *(const bf16x8*)(Asb + (wr * 64 + mi * 16 + c) * 64     \
                                          + (((ks << 2) + quad) ^ (c & 7)) * 8); \
            _Pragma("unroll")                                                    \
            for (int ni = 0; ni < 4; ni++)                                       \
                bfr[ni] = *(const bf16x8*)(Bsb + (wc * 64 + ni * 16 + c) * 64    \
                                          + (((ks << 2) + quad) ^ (c & 7)) * 8); \
            _Pragma("unroll")                                                    \
            for (int mi = 0; mi < 4; mi++)                                       \
                _Pragma("unroll")                                                \
                for (int ni = 0; ni < 4; ni++)                                   \
                    acc[mi][ni] = __builtin_amdgcn_mfma_f32_16x16x32_bf16(       \
                        af[mi], bfr[ni], acc[mi][ni], 0, 0, 0);                  \
        }                                                                        \
        asm volatile("s_waitcnt lgkmcnt(0)\n\ts_barrier" ::: "memory");          \
    }                                                                            \
    const int mBase = rowBase + wr * 64;                                         \
    const int nBase = colBase + wc * 64;

// ---------------------------------------------------------------- fused QKV GEMM
__global__ __launch_bounds__(256, 2)
void gemm_qkv(const bf16* __restrict__ A, const bf16* __restrict__ Bw,
              bf16* __restrict__ Qb, bf16* __restrict__ Kb, bf16* __restrict__ Vtb,
              const float* __restrict__ cosp, const float* __restrict__ sinp,
              float qscale)
{
    __shared__ __align__(16) bf16 Ls[2 * 16384];   // 64KB: 2 x (A 16K + B 16K)

    GEMM_CORE5(A, Bw, D_SZ)

    // wave's 64 cols = exactly one 64-wide head; Q/K/V regions are 64-aligned
    const int hcol = nBase;
    if (hcol < 2560) {
        // ---- RoPE path (Q or K)
        bf16* dst; int hh, Hn; float sc;
        if (hcol < 2048) { dst = Qb; hh = hcol >> 6;        Hn = H_SZ;  sc = qscale; }
        else             { dst = Kb; hh = (hcol >> 6) - 32; Hn = KV_SZ; sc = 1.0f;  }
#pragma unroll
        for (int mi = 0; mi < 4; mi++) {
#pragma unroll
            for (int r = 0; r < 4; r++) {
                int row = mBase + mi * 16 + quad * 4 + r;
                int b = row >> 11;           // S = 2048
                int s = row & 2047;
                const float* cr = cosp + (size_t)s * 32;
                const float* sr = sinp + (size_t)s * 32;
                size_t base = ((size_t)(b * Hn + hh) * S_SZ + s) * 64;
#pragma unroll
                for (int nj = 0; nj < 2; nj++) {
                    int d = nj * 16 + c;          // 0..31
                    float x1 = acc[mi][nj][r];
                    float x2 = acc[mi][nj + 2][r];
                    float cv = cr[d], sv = sr[d];
                    dst[base + d]      = (bf16)((x1 * cv - x2 * sv) * sc);
                    dst[base + d + 32] = (bf16)((x1 * sv + x2 * cv) * sc);
                }
            }
        }
    } else {
        // ---- V path: transposed store (b, kv, d, s)
        const int kvh = (hcol >> 6) - 40;
        const int b   = mBase >> 11;
        const int s0  = mBase & 2047;
#pragma unroll
        for (int nj = 0; nj < 4; nj++) {
            int d = nj * 16 + c;
            size_t base = ((size_t)(b * KV_SZ + kvh) * 64 + d) * (size_t)S_SZ;
#pragma unroll
            for (int mi = 0; mi < 4; mi++) {
                int s = s0 + mi * 16 + quad * 4;
#pragma unroll
                for (int r = 0; r < 4; r++)
                    Vtb[base + s + r] = (bf16)acc[mi][nj][r];
            }
        }
    }
}

// ---------------------------------------------------------------- O-proj GEMM (fp32 out)
__global__ __launch_bounds__(256, 2)
void gemm_out(const bf16* __restrict__ A, const bf16* __restrict__ Bw,
              float* __restrict__ Co, int N, int K)
{
    __shared__ __align__(16) bf16 Ls[2 * 16384];   // 64KB

    GEMM_CORE5(A, Bw, K)

#pragma unroll
    for (int mi = 0; mi < 4; mi++)
#pragma unroll
        for (int ni = 0; ni < 4; ni++) {
            int col = nBase + ni * 16 + c;
#pragma unroll
            for (int r = 0; r < 4; r++) {
                int row = mBase + mi * 16 + quad * 4 + r;
                Co[(size_t)row * N + col] = acc[mi][ni][r];
            }
        }
}

// ---------------------------------------------------------------- flash attention v9
// Pass-count lever: v1-vs-v2 data shows per-pass overhead (~2.24us) is 94% of
// a pass; wall = passes-per-slot x 2.5us. So: KVBLK 64 -> 128 (half the
// passes), ONE 64-row q-tile per block (VGPR ~105, robustly < 128 cliff).
// Block t runs ceil((t+1)/2) passes; grid (32, 64); t = 31-((x+y)&31)
// decorrelates pass-count from XCD and spreads heavy blocks in dispatch order.
// K tile [128][64], V tile [64][128], XOR chunk swizzle (pos = chunk^(row&7),
// low-3-bit XOR) -> staging writes and b128 frag reads conflict-free.
// P per wave: 16 q-rows x 128 k, stride 132. Row-sum via VALU accumulate +
// 2 epilogue shfl_xor (frees ones-frag + l accumulators).
#define PST 132   // P row stride (elems)

__global__ __launch_bounds__(256, 3)
void flash_attn(const bf16* __restrict__ Q, const bf16* __restrict__ Kc,
                const bf16* __restrict__ Vt, bf16* __restrict__ Aout)
{
    __shared__ __align__(16) bf16 Ks[128 * 64];
    __shared__ __align__(16) bf16 Vs[64 * 128];
    __shared__ __align__(16) bf16 Ps[4 * 16 * PST];

    const int tid  = threadIdx.x;
    const int lane = tid & 63;
    const int wave = tid >> 6;
    const int c = lane & 15, quad = lane >> 4;
    const int qloc = wave * 16 + c;      // q index within 64-row tile

    const int t  = 31 - ((blockIdx.x + blockIdx.y) & 31);  // q-tile index
    const int q0 = t << 6;
    const int NP = (t + 2) >> 1;         // number of 128-wide KV passes

    const int bh = blockIdx.y;           // b*H + h
    const int b  = bh >> 5;
    const int h  = bh & 31;
    const int kv = h >> 2;

    const bf16* Qp = Q  + (size_t)bh * (S_SZ * 64);
    const bf16* Kp = Kc + (size_t)(b * KV_SZ + kv) * (S_SZ * 64);
    const bf16* Vp = Vt + (size_t)(b * KV_SZ + kv) * (64 * S_SZ);

    // Q fragments (B-operand layout): n = lane&15, k = quad*8 (+32)
    bf16x8 aq[2];
    {
        const bf16* qa = Qp + (size_t)(q0 + qloc) * 64 + quad * 8;
        aq[0] = *(const bf16x8*)qa;
        aq[1] = *(const bf16x8*)(qa + 32);
    }

    f32x4 o[4] = {};
    float lsum = 0.f;

    // staging maps (256 threads):
    // K: [128 rows k][64 cols d]; lane: rows {sr+32j}, chunk ch, pos ch^(sr&7)
    const int sr = tid >> 3;                   // 0..31
    const int ch = tid & 7;
    const int swk = (ch ^ (sr & 7)) * 8;
    // V: [64 rows d][128 cols k]; lane: row rv, chunks {cv+4j}, pos ^(rv&7)
    const int rv = tid >> 2;                   // 0..63
    const int cv = tid & 3;

    const bf16* Kg = Kp + (size_t)sr * 64 + ch * 8;
    const bf16* Vg = Vp + (size_t)rv * S_SZ + cv * 8;

    uint4 pk[4], pv[4];
#pragma unroll
    for (int j = 0; j < 4; j++) {
        pk[j] = *(const uint4*)(Kg + (size_t)(32 * j) * 64);
        pv[j] = *(const uint4*)(Vg + j * 32);
    }

    bf16* Pw = Ps + (wave * 16) * PST;

    for (int kt = 0; kt < NP; kt++) {
        // stage current tile from prefetch regs (vmcnt waited here by compiler)
#pragma unroll
        for (int j = 0; j < 4; j++) {
            *(uint4*)(Ks + (sr + 32 * j) * 64 + swk) = pk[j];
            *(uint4*)(Vs + rv * 128 + ((cv + 4 * j) ^ (rv & 7)) * 8) = pv[j];
        }
        if (kt + 1 < NP) {   // issue next-tile prefetch; in flight across barriers
            const size_t ko = (size_t)(kt + 1) * 128 * 64;
#pragma unroll
            for (int j = 0; j < 4; j++) {
                pk[j] = *(const uint4*)(Kg + ko + (size_t)(32 * j) * 64);
                pv[j] = *(const uint4*)(Vg + (kt + 1) * 128 + j * 32);
            }
        }
        bar_lgkm();                      // stage visible; no vmcnt drain

        const bool msk = (kt == NP - 1);

        // ---------------- QK^T + softmax numerators, per 64-col half
#pragma unroll
        for (int half = 0; half < 2; half++) {
            f32x4 sc4[4] = {};
#pragma unroll
            for (int ks = 0; ks < 2; ks++) {
                bf16x8 ak4[4];
#pragma unroll
                for (int n4 = 0; n4 < 4; n4++)
                    ak4[n4] = *(const bf16x8*)(Ks + (half * 64 + n4 * 16 + c) * 64
                                               + (((ks << 2) + quad) ^ (c & 7)) * 8);
                __builtin_amdgcn_s_setprio(1);
#pragma unroll
                for (int n4 = 0; n4 < 4; n4++)
                    sc4[n4] = __builtin_amdgcn_mfma_f32_16x16x32_bf16(
                        ak4[n4], aq[ks], sc4[n4], 0, 0, 0);
                __builtin_amdgcn_s_setprio(0);
            }
            const int kbase = kt * 128 + half * 64;
#pragma unroll
            for (int n4 = 0; n4 < 4; n4++) {
                bf16x4 pkk;
#pragma unroll
                for (int r = 0; r < 4; r++) {
                    float p = exp2f(sc4[n4][r]);
                    if (msk && (kbase + n4 * 16 + quad * 4 + r) > (q0 + qloc)) p = 0.f;
                    lsum += p;
                    pkk[r] = (bf16)p;
                }
                *(bf16x4*)(Pw + c * PST + half * 64 + n4 * 16 + quad * 4) = pkk;
            }
        }

        // ---------------- P @ V (P is wave-private: no barrier needed)
#pragma unroll
        for (int ks4 = 0; ks4 < 4; ks4++) {
            bf16x8 av4[4];
#pragma unroll
            for (int d4 = 0; d4 < 4; d4++)
                av4[d4] = *(const bf16x8*)(Vs + (d4 * 16 + c) * 128
                                           + (((ks4 << 2) + quad) ^ (c & 7)) * 8);
            bf16x8 bp = *(const bf16x8*)(Pw + c * PST + ks4 * 32 + quad * 8);
            __builtin_amdgcn_s_setprio(1);
#pragma unroll
            for (int d4 = 0; d4 < 4; d4++)
                o[d4] = __builtin_amdgcn_mfma_f32_16x16x32_bf16(
                    av4[d4], bp, o[d4], 0, 0, 0);
            __builtin_amdgcn_s_setprio(0);
        }
        bar_lgkm();    // all waves' K/V reads done; next pass may overwrite
    }

    // epilogue: row-sum across quads (lanes c, c+16, c+32, c+48), then store
    {
        float s = lsum;
        s += __shfl_xor(s, 16);
        s += __shfl_xor(s, 32);
        float il = 1.f / s;
        bf16* pa = Aout + ((size_t)(b * S_SZ + q0 + qloc)) * D_SZ + h * 64;
#pragma unroll
        for (int d4 = 0; d4 < 4; d4++) {
            bf16x4 w;
#pragma unroll
            for (int r = 0; r < 4; r++) w[r] = (bf16)(o[d4][r] * il);
            *(bf16x4*)(pa + d4 * 16 + quad * 4) = w;
        }
    }
}

// ---------------------------------------------------------------- launcher
extern "C" void kernel_launch(void* const* d_in, const int* in_sizes, int n_in,
                              void* d_out, int out_size, void* d_ws, size_t ws_size,
                              hipStream_t stream) {
    const float* x    = (const float*)d_in[0];
    const float* cosp = (const float*)d_in[1];
    const float* sinp = (const float*)d_in[2];
    const float* Wq   = (const float*)d_in[3];
    const float* Wk   = (const float*)d_in[4];
    const float* Wv   = (const float*)d_in[5];
    const float* Wo   = (const float*)d_in[6];
    float* out = (float*)d_out;

    const int M = M_SZ;            // 4096
    const int D = D_SZ;            // 2048
    const int NKV = KV_SZ * HD_SZ; // 512

    // workspace layout (bf16 elems)
    bf16* xb   = (bf16*)d_ws;                    // M*D
    bf16* Wf   = xb  + (size_t)M * D;            // NQKV*D
    bf16* Qb   = Wf  + (size_t)NQKV * D;         // M*D (b,h,s,64)
    bf16* Kb   = Qb  + (size_t)M * D;            // (b,kv,s,64)
    bf16* Vtb  = Kb  + (size_t)B_SZ * KV_SZ * S_SZ * 64; // (b,kv,64,s)
    bf16* wob  = Vtb + (size_t)B_SZ * KV_SZ * 64 * S_SZ; // D*D
    bf16* attn = xb;    // alias: x dead after QKV GEMM

    const int nx = M * D / 4, n1 = D * D / 4, n2 = NKV * D / 4;

    // fused conversions (x + packed QKV weights + Wo)
    cvt_all<<<(nx + 2 * n1 + 2 * n2 + 255) / 256, 256, 0, stream>>>(
        x, Wq, Wk, Wv, Wo, xb, Wf, wob, nx, n1, n2);

    const float qscale = 0.125f * 1.44269504089f;   // 1/sqrt(hd) * log2(e)

    // fused QKV projection (+RoPE, +V transpose)
    gemm_qkv<<<dim3(NQKV / 128, M / 128), 256, 0, stream>>>(xb, Wf, Qb, Kb, Vtb, cosp, sinp, qscale);

    // flash attention -> attn (b,s,2048) bf16
    flash_attn<<<dim3(32, B_SZ * H_SZ), 256, 0, stream>>>(Qb, Kb, Vtb, attn);

    // out = attn Wo^T (fp32)
    gemm_out<<<dim3(D / 128, M / 128), 256, 0, stream>>>(attn, wob, out, D, D);
}

// Round 10
// 293.739 us; speedup vs baseline: 1.4809x; 1.4809x over previous
//
#include <hip/hip_runtime.h>
#include <hip/hip_bf16.h>

typedef __bf16 bf16;
typedef __attribute__((ext_vector_type(8))) __bf16 bf16x8;
typedef __attribute__((ext_vector_type(4))) __bf16 bf16x4;
typedef __attribute__((ext_vector_type(4))) float f32x4;

// ---------------------------------------------------------------- constants
#define B_SZ 2
#define S_SZ 2048
#define D_SZ 2048
#define H_SZ 32
#define KV_SZ 8
#define HD_SZ 64
#define M_SZ (B_SZ * S_SZ)   // 4096
#define NQKV 3072            // 2048 Q + 512 K + 512 V packed weight rows

// async global->LDS, 16B per lane; LDS dest = wave-uniform base + lane*16
#define GLDS(g, s) __builtin_amdgcn_global_load_lds( \
    (const __attribute__((address_space(1))) void*)(g), \
    (__attribute__((address_space(3))) void*)(s), 16, 0, 0)

// lgkm-only barrier: do NOT drain vmcnt (in-flight global loads cross the
// barrier; their completion is waited where the data is consumed).
__device__ __forceinline__ void bar_lgkm() {
    asm volatile("s_waitcnt lgkmcnt(0)\n\ts_barrier" ::: "memory");
}

// ---------------------------------------------------------------- fused conversions
// single dispatch: x -> xb, [Wq;Wk;Wv] -> Wf, Wo -> wob (all bf16)
__global__ void cvt_all(const float* __restrict__ x, const float* __restrict__ Wq,
                        const float* __restrict__ Wk, const float* __restrict__ Wv,
                        const float* __restrict__ Wo,
                        bf16* __restrict__ xb, bf16* __restrict__ Wf, bf16* __restrict__ wob,
                        int nx, int n1, int n2) {
    int i = blockIdx.x * blockDim.x + threadIdx.x;
    const float* src; bf16* dst; int off;
    if (i < nx)                 { src = x;  dst = xb; off = i; }
    else {
        int j = i - nx;
        if (j < n1)             { src = Wq; dst = Wf; off = j; }
        else if (j < n1 + n2)   { src = Wk; dst = Wf + (size_t)4 * n1; off = j - n1; }
        else if (j < n1 + 2*n2) { src = Wv; dst = Wf + (size_t)4 * (n1 + n2); off = j - n1 - n2; }
        else if (j < 2*n1+2*n2) { src = Wo; dst = wob; off = j - n1 - 2 * n2; }
        else return;
    }
    float4 v = ((const float4*)src)[off];
    bf16x4 o;
    o.x = (bf16)v.x; o.y = (bf16)v.y; o.z = (bf16)v.z; o.w = (bf16)v.w;
    ((bf16x4*)dst)[off] = o;
}

// ---------------------------------------------------------------- GEMM core: 2-phase dbuf
// (proven v8: -18us) 256 threads / 4 waves; wave (wr,wc) owns a 64x64
// quadrant; acc[4][4]. LDS double buffer (2 x 32KB); next tile's 8
// global_load_lds issued BEFORE computing the current tile, in flight across
// the trailing lgkm-only barrier; head waits vmcnt(8) (counted vmcnt).
// XOR chunk swizzle (chunk q of row r at q^(r&7)); staging lane l fetches
// global chunk (l&7)^(l>>3) so LDS writes are linear; b128 reads conflict-free.
#define GEMM_CORE5(A_, B_, Kdim)                                                 \
    const int tid  = threadIdx.x;                                                \
    const int wv   = tid >> 6;                                                   \
    const int lane = tid & 63;                                                   \
    const int c = lane & 15, quad = lane >> 4;                                   \
    const int wr = wv >> 1, wc = wv & 1;                                         \
    const int g8 = lane >> 3;                                                    \
    const int chs = ((lane & 7) ^ g8) * 8;                                       \
    const int rowBase = blockIdx.y * 128;                                        \
    const int colBase = blockIdx.x * 128;                                        \
    const bf16* Ag = A_ + (size_t)(rowBase + wv * 32 + g8) * Kdim + chs;         \
    const bf16* Bg = B_ + (size_t)(colBase + wv * 32 + g8) * Kdim + chs;         \
    f32x4 acc[4][4] = {};                                                        \
    _Pragma("unroll")                                                            \
    for (int j = 0; j < 4; j++) {       /* prologue: stage tile 0 -> buf 0 */    \
        GLDS(Ag + (size_t)(j * 8) * Kdim, Ls + (wv * 32 + j * 8) * 64);          \
        GLDS(Bg + (size_t)(j * 8) * Kdim, Ls + 8192 + (wv * 32 + j * 8) * 64);   \
    }                                                                            \
    for (int k0 = 0; k0 < Kdim; k0 += 64) {                                      \
        bf16* Asb = Ls + ((k0 >> 6) & 1) * 16384;                                \
        bf16* Bsb = Asb + 8192;                                                  \
        if (k0 + 64 < Kdim) {           /* issue next tile into other buf */     \
            bf16* Asn = Ls + ((((k0 >> 6) & 1) ^ 1) * 16384);                    \
            _Pragma("unroll")                                                    \
            for (int j = 0; j < 4; j++) {                                        \
                GLDS(Ag + (size_t)(j * 8) * Kdim + (k0 + 64),                    \
                     Asn + (wv * 32 + j * 8) * 64);                              \
                GLDS(Bg + (size_t)(j * 8) * Kdim + (k0 + 64),                    \
                     Asn + 8192 + (wv * 32 + j * 8) * 64);                       \
            }                                                                    \
            asm volatile("s_waitcnt vmcnt(8)" ::: "memory");                     \
        } else {                                                                 \
            asm volatile("s_waitcnt vmcnt(0)" ::: "memory");                     \
        }                                                                        \
        asm volatile("s_waitcnt lgkmcnt(0)\n\ts_barrier" ::: "memory");          \
        _Pragma("unroll")                                                        \
        for (int ks = 0; ks < 2; ks++) {                                         \
            bf16x8 af[4], bfr[4];                                                \
            _Pragma("unroll")                                                    \
            for (int mi = 0; mi < 4; mi++)                                       \
                af[mi] = *(const bf16x8*)(Asb + (wr * 64 + mi * 16 + c) * 64     \
                                          + (((ks << 2) + quad) ^ (c & 7)) * 8); \
            _Pragma("unroll")                                                    \
            for (int ni = 0; ni < 4; ni++)                                       \
                bfr[ni] = *(const bf16x8*)(Bsb + (wc * 64 + ni * 16 + c) * 64    \
                                          + (((ks << 2) + quad) ^ (c & 7)) * 8); \
            _Pragma("unroll")                                                    \
            for (int mi = 0; mi < 4; mi++)                                       \
                _Pragma("unroll")                                                \
                for (int ni = 0; ni < 4; ni++)                                   \
                    acc[mi][ni] = __builtin_amdgcn_mfma_f32_16x16x32_bf16(       \
                        af[mi], bfr[ni], acc[mi][ni], 0, 0, 0);                  \
        }                                                                        \
        asm volatile("s_waitcnt lgkmcnt(0)\n\ts_barrier" ::: "memory");          \
    }                                                                            \
    const int mBase = rowBase + wr * 64;                                         \
    const int nBase = colBase + wc * 64;

// ---------------------------------------------------------------- fused QKV GEMM
__global__ __launch_bounds__(256, 2)
void gemm_qkv(const bf16* __restrict__ A, const bf16* __restrict__ Bw,
              bf16* __restrict__ Qb, bf16* __restrict__ Kb, bf16* __restrict__ Vtb,
              const float* __restrict__ cosp, const float* __restrict__ sinp,
              float qscale)
{
    __shared__ __align__(16) bf16 Ls[2 * 16384];   // 64KB: 2 x (A 16K + B 16K)

    GEMM_CORE5(A, Bw, D_SZ)

    // wave's 64 cols = exactly one 64-wide head; Q/K/V regions are 64-aligned
    const int hcol = nBase;
    if (hcol < 2560) {
        // ---- RoPE path (Q or K)
        bf16* dst; int hh, Hn; float sc;
        if (hcol < 2048) { dst = Qb; hh = hcol >> 6;        Hn = H_SZ;  sc = qscale; }
        else             { dst = Kb; hh = (hcol >> 6) - 32; Hn = KV_SZ; sc = 1.0f;  }
#pragma unroll
        for (int mi = 0; mi < 4; mi++) {
#pragma unroll
            for (int r = 0; r < 4; r++) {
                int row = mBase + mi * 16 + quad * 4 + r;
                int b = row >> 11;           // S = 2048
                int s = row & 2047;
                const float* cr = cosp + (size_t)s * 32;
                const float* sr = sinp + (size_t)s * 32;
                size_t base = ((size_t)(b * Hn + hh) * S_SZ + s) * 64;
#pragma unroll
                for (int nj = 0; nj < 2; nj++) {
                    int d = nj * 16 + c;          // 0..31
                    float x1 = acc[mi][nj][r];
                    float x2 = acc[mi][nj + 2][r];
                    float cv = cr[d], sv = sr[d];
                    dst[base + d]      = (bf16)((x1 * cv - x2 * sv) * sc);
                    dst[base + d + 32] = (bf16)((x1 * sv + x2 * cv) * sc);
                }
            }
        }
    } else {
        // ---- V path: transposed store (b, kv, d, s)
        const int kvh = (hcol >> 6) - 40;
        const int b   = mBase >> 11;
        const int s0  = mBase & 2047;
#pragma unroll
        for (int nj = 0; nj < 4; nj++) {
            int d = nj * 16 + c;
            size_t base = ((size_t)(b * KV_SZ + kvh) * 64 + d) * (size_t)S_SZ;
#pragma unroll
            for (int mi = 0; mi < 4; mi++) {
                int s = s0 + mi * 16 + quad * 4;
#pragma unroll
                for (int r = 0; r < 4; r++)
                    Vtb[base + s + r] = (bf16)acc[mi][nj][r];
            }
        }
    }
}

// ---------------------------------------------------------------- O-proj GEMM (fp32 out)
__global__ __launch_bounds__(256, 2)
void gemm_out(const bf16* __restrict__ A, const bf16* __restrict__ Bw,
              float* __restrict__ Co, int N, int K)
{
    __shared__ __align__(16) bf16 Ls[2 * 16384];   // 64KB

    GEMM_CORE5(A, Bw, K)

#pragma unroll
    for (int mi = 0; mi < 4; mi++)
#pragma unroll
        for (int ni = 0; ni < 4; ni++) {
            int col = nBase + ni * 16 + c;
#pragma unroll
            for (int r = 0; r < 4; r++) {
                int row = mBase + mi * 16 + quad * 4 + r;
                Co[(size_t)row * N + col] = acc[mi][ni][r];
            }
        }
}

// ---------------------------------------------------------------- flash attention v10
// v5 compute structure (proven 82us; 16 q-rows/wave, paired 64-row tiles
// A=31-i'/B=i') with staging converted to the GEMM-proven 2-phase dbuf:
// K/V double-buffered in LDS, staged by global_load_lds (4 per wave per tile:
// wave w covers rows [w*16,w*16+16), lane l -> row +(l>>3), source chunk
// (l&7)^(l>>3), so linear LDS writes give the same swizzled content map as
// v5 and reads keep pos ^(c&7)). Per pass: issue next tile's 4 GLDS into the
// other buffer -> vmcnt(4) (own tile landed, next in flight across barriers)
// -> barrier -> compute -> lgkm-only barrier. Deletes the 4 uint4 prefetch
// regs + staging ds_writes (lower VGPR than v5 -> no spill risk).
#define PST 72   // P row stride (elems); 2-way bank alias on b64/b128 = free

__global__ __launch_bounds__(256, 3)
void flash_attn(const bf16* __restrict__ Q, const bf16* __restrict__ Kc,
                const bf16* __restrict__ Vt, bf16* __restrict__ Aout)
{
    __shared__ __align__(16) bf16 Ksh[2][64 * 64];
    __shared__ __align__(16) bf16 Vsh[2][64 * 64];
    __shared__ __align__(16) bf16 Ps[2 * 4 * 16 * PST];

    const int tid  = threadIdx.x;
    const int lane = tid & 63;
    const int wave = tid >> 6;
    const int c = lane & 15, quad = lane >> 4;
    const int qloc = wave * 16 + c;      // q index within 64-row tile

    const int i  = (blockIdx.x + blockIdx.y) & 15;   // balanced tile-pair index
    const int tA = 31 - i, tB = i;       // paired q-tiles (uniform 33 computes)
    const int q0A = tA << 6, q0B = tB << 6;

    const int bh = blockIdx.y;           // b*H + h
    const int b  = bh >> 5;
    const int h  = bh & 31;
    const int kv = h >> 2;

    const bf16* Qp = Q  + (size_t)bh * (S_SZ * 64);
    const bf16* Kp = Kc + (size_t)(b * KV_SZ + kv) * (S_SZ * 64);
    const bf16* Vp = Vt + (size_t)(b * KV_SZ + kv) * (64 * S_SZ);

    // Q fragments (B-operand layout): n = lane&15, k = quad*8 (+32)
    bf16x8 aqA[2], aqB[2];
    {
        const bf16* qa = Qp + (size_t)(q0A + qloc) * 64 + quad * 8;
        aqA[0] = *(const bf16x8*)qa;  aqA[1] = *(const bf16x8*)(qa + 32);
        const bf16* qb = Qp + (size_t)(q0B + qloc) * 64 + quad * 8;
        aqB[0] = *(const bf16x8*)qb;  aqB[1] = *(const bf16x8*)(qb + 32);
    }

    f32x4 oA[4] = {}, oB[4] = {};
    f32x4 lA = {}, lB = {};

    bf16x8 ones;
#pragma unroll
    for (int j = 0; j < 8; j++) ones[j] = (bf16)1.0f;

    // glds staging geometry: wave stages rows [wave*16, wave*16+16) of each
    // 64x64 tile; lane l covers row +(l>>3), pre-swizzled source chunk
    const int g8  = lane >> 3;
    const int chs = ((lane & 7) ^ g8) * 8;
    const bf16* KgL = Kp + (size_t)(wave * 16 + g8) * 64 + chs;
    const bf16* VgL = Vp + (size_t)(wave * 16 + g8) * S_SZ + chs;

    bf16* PwA = Ps + wave * 16 * PST;
    bf16* PwB = Ps + (4 + wave) * 16 * PST;

    // prologue: stage tile 0 -> buffer 0
#pragma unroll
    for (int j = 0; j < 2; j++) {
        GLDS(KgL + (size_t)(j * 8) * 64,   &Ksh[0][(wave * 16 + j * 8) * 64]);
        GLDS(VgL + (size_t)(j * 8) * S_SZ, &Vsh[0][(wave * 16 + j * 8) * 64]);
    }

    for (int kt = 0; kt <= tA; kt++) {
        const int cur = kt & 1;
        if (kt < tA) {                   // issue next tile into the other buffer
            const int nxt = cur ^ 1;
#pragma unroll
            for (int j = 0; j < 2; j++) {
                GLDS(KgL + (size_t)(kt + 1) * 4096 + (size_t)(j * 8) * 64,
                     &Ksh[nxt][(wave * 16 + j * 8) * 64]);
                GLDS(VgL + (kt + 1) * 64 + (size_t)(j * 8) * S_SZ,
                     &Vsh[nxt][(wave * 16 + j * 8) * 64]);
            }
            asm volatile("s_waitcnt vmcnt(4)" ::: "memory");  // own tile landed
        } else {
            asm volatile("s_waitcnt vmcnt(0)" ::: "memory");
        }
        asm volatile("s_waitcnt lgkmcnt(0)\n\ts_barrier" ::: "memory");

        const bf16* Kst = Ksh[cur];
        const bf16* Vst = Vsh[cur];

        const bool doB   = (kt <= tB);
        const bool diagA = (kt == tA);
        const bool diagB = (kt == tB);

        // ---------------- QK^T for both tiles over shared K fragments
        f32x4 scA[4] = {}, scB[4] = {};
#pragma unroll
        for (int ks = 0; ks < 2; ks++) {
            bf16x8 ak4[4];
#pragma unroll
            for (int ni = 0; ni < 4; ni++)
                ak4[ni] = *(const bf16x8*)(Kst + (ni * 16 + c) * 64
                                           + (((ks << 2) + quad) ^ (c & 7)) * 8);
            __builtin_amdgcn_s_setprio(1);
#pragma unroll
            for (int ni = 0; ni < 4; ni++)
                scA[ni] = __builtin_amdgcn_mfma_f32_16x16x32_bf16(ak4[ni], aqA[ks], scA[ni], 0, 0, 0);
            if (doB) {
#pragma unroll
                for (int ni = 0; ni < 4; ni++)
                    scB[ni] = __builtin_amdgcn_mfma_f32_16x16x32_bf16(ak4[ni], aqB[ks], scB[ni], 0, 0, 0);
            }
            __builtin_amdgcn_s_setprio(0);
        }

        // ---------------- softmax numerators -> P (uniform diag branch)
        if (diagA) {
#pragma unroll
            for (int ni = 0; ni < 4; ni++) {
                bf16x4 pk;
#pragma unroll
                for (int r = 0; r < 4; r++) {
                    float p = exp2f(scA[ni][r]);
                    if ((ni * 16 + quad * 4 + r) > qloc) p = 0.f;
                    pk[r] = (bf16)p;
                }
                *(bf16x4*)(PwA + c * PST + ni * 16 + quad * 4) = pk;
            }
        } else {
#pragma unroll
            for (int ni = 0; ni < 4; ni++) {
                bf16x4 pk;
#pragma unroll
                for (int r = 0; r < 4; r++) pk[r] = (bf16)exp2f(scA[ni][r]);
                *(bf16x4*)(PwA + c * PST + ni * 16 + quad * 4) = pk;
            }
        }
        if (doB) {
            if (diagB) {
#pragma unroll
                for (int ni = 0; ni < 4; ni++) {
                    bf16x4 pk;
#pragma unroll
                    for (int r = 0; r < 4; r++) {
                        float p = exp2f(scB[ni][r]);
                        if ((ni * 16 + quad * 4 + r) > qloc) p = 0.f;
                        pk[r] = (bf16)p;
                    }
                    *(bf16x4*)(PwB + c * PST + ni * 16 + quad * 4) = pk;
                }
            } else {
#pragma unroll
                for (int ni = 0; ni < 4; ni++) {
                    bf16x4 pk;
#pragma unroll
                    for (int r = 0; r < 4; r++) pk[r] = (bf16)exp2f(scB[ni][r]);
                    *(bf16x4*)(PwB + c * PST + ni * 16 + quad * 4) = pk;
                }
            }
        }

        // ---------------- P @ V for both tiles over shared V fragments
#pragma unroll
        for (int ks = 0; ks < 2; ks++) {
            bf16x8 av4[4];
#pragma unroll
            for (int ni = 0; ni < 4; ni++)
                av4[ni] = *(const bf16x8*)(Vst + (ni * 16 + c) * 64
                                           + (((ks << 2) + quad) ^ (c & 7)) * 8);
            bf16x8 bpA = *(const bf16x8*)(PwA + c * PST + ks * 32 + quad * 8);
            __builtin_amdgcn_s_setprio(1);
            lA = __builtin_amdgcn_mfma_f32_16x16x32_bf16(ones, bpA, lA, 0, 0, 0);
#pragma unroll
            for (int ni = 0; ni < 4; ni++)
                oA[ni] = __builtin_amdgcn_mfma_f32_16x16x32_bf16(av4[ni], bpA, oA[ni], 0, 0, 0);
            __builtin_amdgcn_s_setprio(0);
            if (doB) {
                bf16x8 bpB = *(const bf16x8*)(PwB + c * PST + ks * 32 + quad * 8);
                __builtin_amdgcn_s_setprio(1);
                lB = __builtin_amdgcn_mfma_f32_16x16x32_bf16(ones, bpB, lB, 0, 0, 0);
#pragma unroll
                for (int ni = 0; ni < 4; ni++)
                    oB[ni] = __builtin_amdgcn_mfma_f32_16x16x32_bf16(av4[ni], bpB, oB[ni], 0, 0, 0);
                __builtin_amdgcn_s_setprio(0);
            }
        }
        bar_lgkm();    // all waves' reads of buf[cur] done; next pass's glds may overwrite
    }

    // epilogue: o[ni][r] = O[q=c][d=ni*16+quad*4+r]; packed 8B stores
    {
        float ila = 1.f / lA[0];
        float ilb = 1.f / lB[0];
        bf16* pa = Aout + ((size_t)(b * S_SZ + q0A + qloc)) * D_SZ + h * 64;
        bf16* pb = Aout + ((size_t)(b * S_SZ + q0B + qloc)) * D_SZ + h * 64;
#pragma unroll
        for (int ni = 0; ni < 4; ni++) {
            bf16x4 wa, wb;
#pragma unroll
            for (int r = 0; r < 4; r++) {
                wa[r] = (bf16)(oA[ni][r] * ila);
                wb[r] = (bf16)(oB[ni][r] * ilb);
            }
            *(bf16x4*)(pa + ni * 16 + quad * 4) = wa;
            *(bf16x4*)(pb + ni * 16 + quad * 4) = wb;
        }
    }
}

// ---------------------------------------------------------------- launcher
extern "C" void kernel_launch(void* const* d_in, const int* in_sizes, int n_in,
                              void* d_out, int out_size, void* d_ws, size_t ws_size,
                              hipStream_t stream) {
    const float* x    = (const float*)d_in[0];
    const float* cosp = (const float*)d_in[1];
    const float* sinp = (const float*)d_in[2];
    const float* Wq   = (const float*)d_in[3];
    const float* Wk   = (const float*)d_in[4];
    const float* Wv   = (const float*)d_in[5];
    const float* Wo   = (const float*)d_in[6];
    float* out = (float*)d_out;

    const int M = M_SZ;            // 4096
    const int D = D_SZ;            // 2048
    const int NKV = KV_SZ * HD_SZ; // 512

    // workspace layout (bf16 elems)
    bf16* xb   = (bf16*)d_ws;                    // M*D
    bf16* Wf   = xb  + (size_t)M * D;            // NQKV*D
    bf16* Qb   = Wf  + (size_t)NQKV * D;         // M*D (b,h,s,64)
    bf16* Kb   = Qb  + (size_t)M * D;            // (b,kv,s,64)
    bf16* Vtb  = Kb  + (size_t)B_SZ * KV_SZ * S_SZ * 64; // (b,kv,64,s)
    bf16* wob  = Vtb + (size_t)B_SZ * KV_SZ * 64 * S_SZ; // D*D
    bf16* attn = xb;    // alias: x dead after QKV GEMM

    const int nx = M * D / 4, n1 = D * D / 4, n2 = NKV * D / 4;

    // fused conversions (x + packed QKV weights + Wo)
    cvt_all<<<(nx + 2 * n1 + 2 * n2 + 255) / 256, 256, 0, stream>>>(
        x, Wq, Wk, Wv, Wo, xb, Wf, wob, nx, n1, n2);

    const float qscale = 0.125f * 1.44269504089f;   // 1/sqrt(hd) * log2(e)

    // fused QKV projection (+RoPE, +V transpose)
    gemm_qkv<<<dim3(NQKV / 128, M / 128), 256, 0, stream>>>(xb, Wf, Qb, Kb, Vtb, cosp, sinp, qscale);

    // flash attention -> attn (b,s,2048) bf16
    flash_attn<<<dim3(16, B_SZ * H_SZ), 256, 0, stream>>>(Qb, Kb, Vtb, attn);

    // out = attn Wo^T (fp32)
    gemm_out<<<dim3(D / 128, M / 128), 256, 0, stream>>>(attn, wob, out, D, D);
}

// Round 11
// 289.498 us; speedup vs baseline: 1.5026x; 1.0146x over previous
//
#include <hip/hip_runtime.h>
#include <hip/hip_bf16.h>

typedef __bf16 bf16;
typedef __attribute__((ext_vector_type(8))) __bf16 bf16x8;
typedef __attribute__((ext_vector_type(4))) __bf16 bf16x4;
typedef __attribute__((ext_vector_type(4))) float f32x4;

// ---------------------------------------------------------------- constants
#define B_SZ 2
#define S_SZ 2048
#define D_SZ 2048
#define H_SZ 32
#define KV_SZ 8
#define HD_SZ 64
#define M_SZ (B_SZ * S_SZ)   // 4096
#define NQKV 3072            // 2048 Q + 512 K + 512 V packed weight rows

// async global->LDS, 16B per lane; LDS dest = wave-uniform base + lane*16
#define GLDS(g, s) __builtin_amdgcn_global_load_lds( \
    (const __attribute__((address_space(1))) void*)(g), \
    (__attribute__((address_space(3))) void*)(s), 16, 0, 0)

// lgkm-only barrier: do NOT drain vmcnt (in-flight global loads cross the
// barrier; their completion is waited where the data is consumed).
__device__ __forceinline__ void bar_lgkm() {
    asm volatile("s_waitcnt lgkmcnt(0)\n\ts_barrier" ::: "memory");
}

// ---------------------------------------------------------------- fused conversions
// single dispatch: x -> xb, [Wq;Wk;Wv] -> Wf, Wo -> wob (all bf16)
__global__ void cvt_all(const float* __restrict__ x, const float* __restrict__ Wq,
                        const float* __restrict__ Wk, const float* __restrict__ Wv,
                        const float* __restrict__ Wo,
                        bf16* __restrict__ xb, bf16* __restrict__ Wf, bf16* __restrict__ wob,
                        int nx, int n1, int n2) {
    int i = blockIdx.x * blockDim.x + threadIdx.x;
    const float* src; bf16* dst; int off;
    if (i < nx)                 { src = x;  dst = xb; off = i; }
    else {
        int j = i - nx;
        if (j < n1)             { src = Wq; dst = Wf; off = j; }
        else if (j < n1 + n2)   { src = Wk; dst = Wf + (size_t)4 * n1; off = j - n1; }
        else if (j < n1 + 2*n2) { src = Wv; dst = Wf + (size_t)4 * (n1 + n2); off = j - n1 - n2; }
        else if (j < 2*n1+2*n2) { src = Wo; dst = wob; off = j - n1 - 2 * n2; }
        else return;
    }
    float4 v = ((const float4*)src)[off];
    bf16x4 o;
    o.x = (bf16)v.x; o.y = (bf16)v.y; o.z = (bf16)v.z; o.w = (bf16)v.w;
    ((bf16x4*)dst)[off] = o;
}

// ---------------------------------------------------------------- GEMM core: 2-phase dbuf
// (proven v8: -18us) 256 threads / 4 waves; wave (wr,wc) owns a 64x64
// quadrant; acc[4][4]. LDS double buffer (2 x 32KB); next tile's 8
// global_load_lds issued BEFORE computing the current tile, in flight across
// the trailing lgkm-only barrier; head waits vmcnt(8) (counted vmcnt).
// XOR chunk swizzle (chunk q of row r at q^(r&7)); staging lane l fetches
// global chunk (l&7)^(l>>3) so LDS writes are linear; b128 reads conflict-free.
#define GEMM_CORE5(A_, B_, Kdim)                                                 \
    const int tid  = threadIdx.x;                                                \
    const int wv   = tid >> 6;                                                   \
    const int lane = tid & 63;                                                   \
    const int c = lane & 15, quad = lane >> 4;                                   \
    const int wr = wv >> 1, wc = wv & 1;                                         \
    const int g8 = lane >> 3;                                                    \
    const int chs = ((lane & 7) ^ g8) * 8;                                       \
    const int rowBase = blockIdx.y * 128;                                        \
    const int colBase = blockIdx.x * 128;                                        \
    const bf16* Ag = A_ + (size_t)(rowBase + wv * 32 + g8) * Kdim + chs;         \
    const bf16* Bg = B_ + (size_t)(colBase + wv * 32 + g8) * Kdim + chs;         \
    f32x4 acc[4][4] = {};                                                        \
    _Pragma("unroll")                                                            \
    for (int j = 0; j < 4; j++) {       /* prologue: stage tile 0 -> buf 0 */    \
        GLDS(Ag + (size_t)(j * 8) * Kdim, Ls + (wv * 32 + j * 8) * 64);          \
        GLDS(Bg + (size_t)(j * 8) * Kdim, Ls + 8192 + (wv * 32 + j * 8) * 64);   \
    }                                                                            \
    for (int k0 = 0; k0 < Kdim; k0 += 64) {                                      \
        bf16* Asb = Ls + ((k0 >> 6) & 1) * 16384;                                \
        bf16* Bsb = Asb + 8192;                                                  \
        if (k0 + 64 < Kdim) {           /* issue next tile into other buf */     \
            bf16* Asn = Ls + ((((k0 >> 6) & 1) ^ 1) * 16384);                    \
            _Pragma("unroll")                                                    \
            for (int j = 0; j < 4; j++) {                                        \
                GLDS(Ag + (size_t)(j * 8) * Kdim + (k0 + 64),                    \
                     Asn + (wv * 32 + j * 8) * 64);                              \
                GLDS(Bg + (size_t)(j * 8) * Kdim + (k0 + 64),                    \
                     Asn + 8192 + (wv * 32 + j * 8) * 64);                       \
            }                                                                    \
            asm volatile("s_waitcnt vmcnt(8)" ::: "memory");                     \
        } else {                                                                 \
            asm volatile("s_waitcnt vmcnt(0)" ::: "memory");                     \
        }                                                                        \
        asm volatile("s_waitcnt lgkmcnt(0)\n\ts_barrier" ::: "memory");          \
        _Pragma("unroll")                                                        \
        for (int ks = 0; ks < 2; ks++) {                                         \
            bf16x8 af[4], bfr[4];                                                \
            _Pragma("unroll")                                                    \
            for (int mi = 0; mi < 4; mi++)                                       \
                af[mi] = *(const bf16x8*)(Asb + (wr * 64 + mi * 16 + c) * 64     \
                                          + (((ks << 2) + quad) ^ (c & 7)) * 8); \
            _Pragma("unroll")                                                    \
            for (int ni = 0; ni < 4; ni++)                                       \
                bfr[ni] = *(const bf16x8*)(Bsb + (wc * 64 + ni * 16 + c) * 64    \
                                          + (((ks << 2) + quad) ^ (c & 7)) * 8); \
            _Pragma("unroll")                                                    \
            for (int mi = 0; mi < 4; mi++)                                       \
                _Pragma("unroll")                                                \
                for (int ni = 0; ni < 4; ni++)                                   \
                    acc[mi][ni] = __builtin_amdgcn_mfma_f32_16x16x32_bf16(       \
                        af[mi], bfr[ni], acc[mi][ni], 0, 0, 0);                  \
        }                                                                        \
        asm volatile("s_waitcnt lgkmcnt(0)\n\ts_barrier" ::: "memory");          \
    }                                                                            \
    const int mBase = rowBase + wr * 64;                                         \
    const int nBase = colBase + wc * 64;

// ---------------------------------------------------------------- fused QKV GEMM
__global__ __launch_bounds__(256, 2)
void gemm_qkv(const bf16* __restrict__ A, const bf16* __restrict__ Bw,
              bf16* __restrict__ Qb, bf16* __restrict__ Kb, bf16* __restrict__ Vtb,
              const float* __restrict__ cosp, const float* __restrict__ sinp,
              float qscale)
{
    __shared__ __align__(16) bf16 Ls[2 * 16384];   // 64KB: 2 x (A 16K + B 16K)

    GEMM_CORE5(A, Bw, D_SZ)

    // wave's 64 cols = exactly one 64-wide head; Q/K/V regions are 64-aligned
    const int hcol = nBase;
    if (hcol < 2560) {
        // ---- RoPE path (Q or K)
        bf16* dst; int hh, Hn; float sc;
        if (hcol < 2048) { dst = Qb; hh = hcol >> 6;        Hn = H_SZ;  sc = qscale; }
        else             { dst = Kb; hh = (hcol >> 6) - 32; Hn = KV_SZ; sc = 1.0f;  }
#pragma unroll
        for (int mi = 0; mi < 4; mi++) {
#pragma unroll
            for (int r = 0; r < 4; r++) {
                int row = mBase + mi * 16 + quad * 4 + r;
                int b = row >> 11;           // S = 2048
                int s = row & 2047;
                const float* cr = cosp + (size_t)s * 32;
                const float* sr = sinp + (size_t)s * 32;
                size_t base = ((size_t)(b * Hn + hh) * S_SZ + s) * 64;
#pragma unroll
                for (int nj = 0; nj < 2; nj++) {
                    int d = nj * 16 + c;          // 0..31
                    float x1 = acc[mi][nj][r];
                    float x2 = acc[mi][nj + 2][r];
                    float cv = cr[d], sv = sr[d];
                    dst[base + d]      = (bf16)((x1 * cv - x2 * sv) * sc);
                    dst[base + d + 32] = (bf16)((x1 * sv + x2 * cv) * sc);
                }
            }
        }
    } else {
        // ---- V path: transposed store (b, kv, d, s)
        const int kvh = (hcol >> 6) - 40;
        const int b   = mBase >> 11;
        const int s0  = mBase & 2047;
#pragma unroll
        for (int nj = 0; nj < 4; nj++) {
            int d = nj * 16 + c;
            size_t base = ((size_t)(b * KV_SZ + kvh) * 64 + d) * (size_t)S_SZ;
#pragma unroll
            for (int mi = 0; mi < 4; mi++) {
                int s = s0 + mi * 16 + quad * 4;
#pragma unroll
                for (int r = 0; r < 4; r++)
                    Vtb[base + s + r] = (bf16)acc[mi][nj][r];
            }
        }
    }
}

// ---------------------------------------------------------------- O-proj GEMM (fp32 out)
__global__ __launch_bounds__(256, 2)
void gemm_out(const bf16* __restrict__ A, const bf16* __restrict__ Bw,
              float* __restrict__ Co, int N, int K)
{
    __shared__ __align__(16) bf16 Ls[2 * 16384];   // 64KB

    GEMM_CORE5(A, Bw, K)

#pragma unroll
    for (int mi = 0; mi < 4; mi++)
#pragma unroll
        for (int ni = 0; ni < 4; ni++) {
            int col = nBase + ni * 16 + c;
#pragma unroll
            for (int r = 0; r < 4; r++) {
                int row = mBase + mi * 16 + quad * 4 + r;
                Co[(size_t)row * N + col] = acc[mi][ni][r];
            }
        }
}

// ---------------------------------------------------------------- flash attention v11
// v5/v8 compute structure (proven 82us; reg-staging, 16 q-rows/wave, paired
// 64-row tiles A=31-i'/B=i') + K/V LDS DOUBLE BUFFER -> ONE barrier per pass
// (33 instead of 66). Safety: pass kt writes buf[kt&1], whose previous
// readers were pass kt-2; any wave staging pass kt has passed the barrier of
// pass kt-1, which requires all waves to have finished compute of kt-2 ->
// no WAR window. P is wave-private (written+read by the same wave between
// stage and next barrier) -> no cross-wave hazard. Register cost: +0.
#define PST 72   // P row stride (elems); 2-way bank alias on b64/b128 = free

__global__ __launch_bounds__(256, 3)
void flash_attn(const bf16* __restrict__ Q, const bf16* __restrict__ Kc,
                const bf16* __restrict__ Vt, bf16* __restrict__ Aout)
{
    __shared__ __align__(16) bf16 Ksh[2][64 * 64];
    __shared__ __align__(16) bf16 Vsh[2][64 * 64];
    __shared__ __align__(16) bf16 Ps[2 * 4 * 16 * PST];

    const int tid  = threadIdx.x;
    const int lane = tid & 63;
    const int wave = tid >> 6;
    const int c = lane & 15, quad = lane >> 4;
    const int qloc = wave * 16 + c;      // q index within 64-row tile

    const int i  = (blockIdx.x + blockIdx.y) & 15;   // balanced tile-pair index
    const int tA = 31 - i, tB = i;       // paired q-tiles (uniform 33 computes)
    const int q0A = tA << 6, q0B = tB << 6;

    const int bh = blockIdx.y;           // b*H + h
    const int b  = bh >> 5;
    const int h  = bh & 31;
    const int kv = h >> 2;

    const bf16* Qp = Q  + (size_t)bh * (S_SZ * 64);
    const bf16* Kp = Kc + (size_t)(b * KV_SZ + kv) * (S_SZ * 64);
    const bf16* Vp = Vt + (size_t)(b * KV_SZ + kv) * (64 * S_SZ);

    // Q fragments (B-operand layout): n = lane&15, k = quad*8 (+32)
    bf16x8 aqA[2], aqB[2];
    {
        const bf16* qa = Qp + (size_t)(q0A + qloc) * 64 + quad * 8;
        aqA[0] = *(const bf16x8*)qa;  aqA[1] = *(const bf16x8*)(qa + 32);
        const bf16* qb = Qp + (size_t)(q0B + qloc) * 64 + quad * 8;
        aqB[0] = *(const bf16x8*)qb;  aqB[1] = *(const bf16x8*)(qb + 32);
    }

    f32x4 oA[4] = {}, oB[4] = {};
    f32x4 lA = {}, lB = {};

    bf16x8 ones;
#pragma unroll
    for (int j = 0; j < 8; j++) ones[j] = (bf16)1.0f;

    // staging: 256 threads cover 64x64 tile, 2 rows-of-16B each; XOR swizzle
    const int srow = tid >> 3;                 // 0..31
    const int ch   = tid & 7;                  // global 16B chunk index
    const int sws  = (ch ^ (srow & 7)) * 8;    // swizzled LDS chunk offset (elems)
    const bf16* Kg0 = Kp + (size_t)srow * 64 + ch * 8;
    const bf16* Kg1 = Kp + (size_t)(srow + 32) * 64 + ch * 8;
    const bf16* Vg0 = Vp + (size_t)srow * S_SZ + ch * 8;
    const bf16* Vg1 = Vp + (size_t)(srow + 32) * S_SZ + ch * 8;

    uint4 pk0 = *(const uint4*)Kg0, pk1 = *(const uint4*)Kg1;
    uint4 pv0 = *(const uint4*)Vg0, pv1 = *(const uint4*)Vg1;

    bf16* PwA = Ps + wave * 16 * PST;
    bf16* PwB = Ps + (4 + wave) * 16 * PST;

    for (int kt = 0; kt <= tA; kt++) {
        bf16* Kst = &Ksh[kt & 1][0];
        bf16* Vst = &Vsh[kt & 1][0];
        // stage current tile into this pass's buffer (regs loaded a pass ago)
        *(uint4*)(Kst + srow * 64 + sws)        = pk0;
        *(uint4*)(Kst + (srow + 32) * 64 + sws) = pk1;   // (srow+32)&7 == srow&7
        *(uint4*)(Vst + srow * 64 + sws)        = pv0;
        *(uint4*)(Vst + (srow + 32) * 64 + sws) = pv1;
        if (kt < tA) {   // issue next-tile prefetch; in flight across the barrier
            pk0 = *(const uint4*)(Kg0 + (size_t)(kt + 1) * 4096);
            pk1 = *(const uint4*)(Kg1 + (size_t)(kt + 1) * 4096);
            pv0 = *(const uint4*)(Vg0 + (kt + 1) * 64);
            pv1 = *(const uint4*)(Vg1 + (kt + 1) * 64);
        }
        bar_lgkm();      // ONE barrier per pass: stage visible; no vmcnt drain

        const bool doB   = (kt <= tB);
        const bool diagA = (kt == tA);
        const bool diagB = (kt == tB);

        // ---------------- QK^T for both tiles over shared K fragments
        f32x4 scA[4] = {}, scB[4] = {};
#pragma unroll
        for (int ks = 0; ks < 2; ks++) {
            bf16x8 ak4[4];
#pragma unroll
            for (int ni = 0; ni < 4; ni++)
                ak4[ni] = *(const bf16x8*)(Kst + (ni * 16 + c) * 64
                                           + (((ks << 2) + quad) ^ (c & 7)) * 8);
            __builtin_amdgcn_s_setprio(1);
#pragma unroll
            for (int ni = 0; ni < 4; ni++)
                scA[ni] = __builtin_amdgcn_mfma_f32_16x16x32_bf16(ak4[ni], aqA[ks], scA[ni], 0, 0, 0);
            if (doB) {
#pragma unroll
                for (int ni = 0; ni < 4; ni++)
                    scB[ni] = __builtin_amdgcn_mfma_f32_16x16x32_bf16(ak4[ni], aqB[ks], scB[ni], 0, 0, 0);
            }
            __builtin_amdgcn_s_setprio(0);
        }

        // ---------------- softmax numerators -> P (uniform diag branch)
        if (diagA) {
#pragma unroll
            for (int ni = 0; ni < 4; ni++) {
                bf16x4 pk;
#pragma unroll
                for (int r = 0; r < 4; r++) {
                    float p = exp2f(scA[ni][r]);
                    if ((ni * 16 + quad * 4 + r) > qloc) p = 0.f;
                    pk[r] = (bf16)p;
                }
                *(bf16x4*)(PwA + c * PST + ni * 16 + quad * 4) = pk;
            }
        } else {
#pragma unroll
            for (int ni = 0; ni < 4; ni++) {
                bf16x4 pk;
#pragma unroll
                for (int r = 0; r < 4; r++) pk[r] = (bf16)exp2f(scA[ni][r]);
                *(bf16x4*)(PwA + c * PST + ni * 16 + quad * 4) = pk;
            }
        }
        if (doB) {
            if (diagB) {
#pragma unroll
                for (int ni = 0; ni < 4; ni++) {
                    bf16x4 pk;
#pragma unroll
                    for (int r = 0; r < 4; r++) {
                        float p = exp2f(scB[ni][r]);
                        if ((ni * 16 + quad * 4 + r) > qloc) p = 0.f;
                        pk[r] = (bf16)p;
                    }
                    *(bf16x4*)(PwB + c * PST + ni * 16 + quad * 4) = pk;
                }
            } else {
#pragma unroll
                for (int ni = 0; ni < 4; ni++) {
                    bf16x4 pk;
#pragma unroll
                    for (int r = 0; r < 4; r++) pk[r] = (bf16)exp2f(scB[ni][r]);
                    *(bf16x4*)(PwB + c * PST + ni * 16 + quad * 4) = pk;
                }
            }
        }

        // ---------------- P @ V for both tiles over shared V fragments
#pragma unroll
        for (int ks = 0; ks < 2; ks++) {
            bf16x8 av4[4];
#pragma unroll
            for (int ni = 0; ni < 4; ni++)
                av4[ni] = *(const bf16x8*)(Vst + (ni * 16 + c) * 64
                                           + (((ks << 2) + quad) ^ (c & 7)) * 8);
            bf16x8 bpA = *(const bf16x8*)(PwA + c * PST + ks * 32 + quad * 8);
            __builtin_amdgcn_s_setprio(1);
            lA = __builtin_amdgcn_mfma_f32_16x16x32_bf16(ones, bpA, lA, 0, 0, 0);
#pragma unroll
            for (int ni = 0; ni < 4; ni++)
                oA[ni] = __builtin_amdgcn_mfma_f32_16x16x32_bf16(av4[ni], bpA, oA[ni], 0, 0, 0);
            __builtin_amdgcn_s_setprio(0);
            if (doB) {
                bf16x8 bpB = *(const bf16x8*)(PwB + c * PST + ks * 32 + quad * 8);
                __builtin_amdgcn_s_setprio(1);
                lB = __builtin_amdgcn_mfma_f32_16x16x32_bf16(ones, bpB, lB, 0, 0, 0);
#pragma unroll
                for (int ni = 0; ni < 4; ni++)
                    oB[ni] = __builtin_amdgcn_mfma_f32_16x16x32_bf16(av4[ni], bpB, oB[ni], 0, 0, 0);
                __builtin_amdgcn_s_setprio(0);
            }
        }
        // no trailing barrier: next pass writes the OTHER buffer (dbuf WAR-safe)
    }

    // epilogue: o[ni][r] = O[q=c][d=ni*16+quad*4+r]; packed 8B stores
    {
        float ila = 1.f / lA[0];
        float ilb = 1.f / lB[0];
        bf16* pa = Aout + ((size_t)(b * S_SZ + q0A + qloc)) * D_SZ + h * 64;
        bf16* pb = Aout + ((size_t)(b * S_SZ + q0B + qloc)) * D_SZ + h * 64;
#pragma unroll
        for (int ni = 0; ni < 4; ni++) {
            bf16x4 wa, wb;
#pragma unroll
            for (int r = 0; r < 4; r++) {
                wa[r] = (bf16)(oA[ni][r] * ila);
                wb[r] = (bf16)(oB[ni][r] * ilb);
            }
            *(bf16x4*)(pa + ni * 16 + quad * 4) = wa;
            *(bf16x4*)(pb + ni * 16 + quad * 4) = wb;
        }
    }
}

// ---------------------------------------------------------------- launcher
extern "C" void kernel_launch(void* const* d_in, const int* in_sizes, int n_in,
                              void* d_out, int out_size, void* d_ws, size_t ws_size,
                              hipStream_t stream) {
    const float* x    = (const float*)d_in[0];
    const float* cosp = (const float*)d_in[1];
    const float* sinp = (const float*)d_in[2];
    const float* Wq   = (const float*)d_in[3];
    const float* Wk   = (const float*)d_in[4];
    const float* Wv   = (const float*)d_in[5];
    const float* Wo   = (const float*)d_in[6];
    float* out = (float*)d_out;

    const int M = M_SZ;            // 4096
    const int D = D_SZ;            // 2048
    const int NKV = KV_SZ * HD_SZ; // 512

    // workspace layout (bf16 elems)
    bf16* xb   = (bf16*)d_ws;                    // M*D
    bf16* Wf   = xb  + (size_t)M * D;            // NQKV*D
    bf16* Qb   = Wf  + (size_t)NQKV * D;         // M*D (b,h,s,64)
    bf16* Kb   = Qb  + (size_t)M * D;            // (b,kv,s,64)
    bf16* Vtb  = Kb  + (size_t)B_SZ * KV_SZ * S_SZ * 64; // (b,kv,64,s)
    bf16* wob  = Vtb + (size_t)B_SZ * KV_SZ * 64 * S_SZ; // D*D
    bf16* attn = xb;    // alias: x dead after QKV GEMM

    const int nx = M * D / 4, n1 = D * D / 4, n2 = NKV * D / 4;

    // fused conversions (x + packed QKV weights + Wo)
    cvt_all<<<(nx + 2 * n1 + 2 * n2 + 255) / 256, 256, 0, stream>>>(
        x, Wq, Wk, Wv, Wo, xb, Wf, wob, nx, n1, n2);

    const float qscale = 0.125f * 1.44269504089f;   // 1/sqrt(hd) * log2(e)

    // fused QKV projection (+RoPE, +V transpose)
    gemm_qkv<<<dim3(NQKV / 128, M / 128), 256, 0, stream>>>(xb, Wf, Qb, Kb, Vtb, cosp, sinp, qscale);

    // flash attention -> attn (b,s,2048) bf16
    flash_attn<<<dim3(16, B_SZ * H_SZ), 256, 0, stream>>>(Qb, Kb, Vtb, attn);

    // out = attn Wo^T (fp32)
    gemm_out<<<dim3(D / 128, M / 128), 256, 0, stream>>>(attn, wob, out, D, D);
}